// Round 15
// baseline (1322.303 us; speedup 1.0000x reference)
//
#include <hip/hip_runtime.h>
#include <hip/hip_bf16.h>

typedef __attribute__((ext_vector_type(8))) short bf16x8_t;
typedef __attribute__((ext_vector_type(4))) float f32x4_t;
typedef __attribute__((ext_vector_type(8))) unsigned short u16x8_t;

__device__ inline unsigned short bfr(float f) {
    __hip_bfloat16 h = __float2bfloat16(f);   // RNE
    return *reinterpret_cast<unsigned short*>(&h);
}

__device__ inline u16x8_t cvt8(float4 x, float4 y) {
    u16x8_t v;
    v[0] = bfr(x.x); v[1] = bfr(x.y); v[2] = bfr(x.z); v[3] = bfr(x.w);
    v[4] = bfr(y.x); v[5] = bfr(y.y); v[6] = bfr(y.z); v[7] = bfr(y.w);
    return v;
}

// ---- merged 128x128-tile GEMM+LSE, fused f32->bf16, BK=32, 6 blocks/CU ----
// R15 = R13 with BK 64->32: LDS buffer 16KB (+offsets ~18.5KB) -> 6 blocks/CU
// (launch_bounds(256,6)), halving each thread's staging chain (8 float4 vs
// 16) and deepening inter-block latency cover (5 siblings per barrier).
// blocks (XCD-swizzled over 4192 = 8*524): lb 0..2591 overlap (8 batches x
// 18x18, supertiled 3 sc x (18 brow x 6 bcol) => B-panels L2-resident),
// lb 2592..4191 tile (64 batches x 5x5, rows>=576 duplicated & masked).
// Per K32-step: load 8 float4 (A+B), cvt->bf16, ds_write 16KB buffer, sync,
// 8 ds_read_b128 + 16 MFMA, sync.
// Swizzle (R8-verified 0-conflict at BK=32): 16B-chunk phys = logical ^
// ((row>>1)&3) on global source + ds_read; LDS layout linear.
// ws float layout:
// [0) rs_ov 18432 | [18432) cs_ov 18432 | [36864) dg_ov 18432
// [55296) rs_t 36864 | [92160) cs_t 36864 | [129024) dg_t 36864 -> 165888
__global__ __launch_bounds__(256, 6) void gemm128_lse_all(
    const float* __restrict__ z1, const float* __restrict__ z2,
    float* __restrict__ ws) {
    const int tid  = threadIdx.x;
    const int lane = tid & 63;
    const int w    = tid >> 6;        // 0..3
    const int wM   = w >> 1;          // 0..1 (rows: wM*64)
    const int wN   = w & 1;           // 0..1 (cols: wN*64)
    const int lr   = lane & 15;
    const int lg   = lane >> 4;       // 0..3

    // T1: XCD-aware bijective swizzle over 4192 = 8*524 blocks
    const int bid = blockIdx.x;
    const int lb  = (bid & 7) * 524 + (bid >> 3);

    int M, batch, brow, bcol;
    float inv_tau;
    float *rs, *cs, *dg;
    bool ov = (lb < 2592);
    if (ov) {
        M = 2304; inv_tau = 1.0f / 0.07f;
        rs = ws; cs = ws + 18432; dg = ws + 36864;
        batch = lb / 324;
        int rem = lb - batch * 324;
        int sc = rem / 108, r2 = rem - sc * 108;
        brow = r2 / 6;
        bcol = sc * 6 + (r2 - brow * 6);
    } else {
        M = 576; inv_tau = 1.0f / 0.2f;
        rs = ws + 55296; cs = ws + 92160; dg = ws + 129024;
        int tl = lb - 2592;
        batch = tl / 25;
        int rem = tl - batch * 25;
        brow = rem / 5;
        bcol = rem - brow * 5;
    }

    __shared__ unsigned short smem[8192];    // A[128][32] + B[128][32], 16 KiB
    __shared__ int offA[128], offB[128];

    if (tid < 128) {
        int r = brow * 128 + tid;
        int off;
        if (ov) {
            int b = r / 288, rm = r % 288, h = rm / 12, j = rm % 12;
            off = ((b * 8 + batch) * 576 + h * 24 + 12 + j) * 768;
        } else {
            off = ((r < M) ? (batch * 576 + r) : (batch * 576)) * 768;
        }
        offA[tid] = off;
    } else {
        int c = bcol * 128 + (tid - 128);
        int off;
        if (ov) {
            int b = c / 288, rm = c % 288, h = rm / 12, j = rm % 12;
            off = ((b * 8 + ((batch + 1) & 7)) * 576 + h * 24 + j) * 768;
        } else {
            off = ((c < M) ? (batch * 576 + c) : (batch * 576)) * 768;
        }
        offB[tid - 128] = off;
    }
    __syncthreads();

    // staging: thread covers rows tid>>2 and 64+(tid>>2), phys 16B-chunk
    // tid&3; source fetches logical chunk (tid&3)^((row>>1)&3) = 8 floats.
    int srcA[2], srcB[2], dA[2], dB[2];
#pragma unroll
    for (int r = 0; r < 2; ++r) {
        int row = r * 64 + (tid >> 2);
        int cs_ = (((tid & 3) ^ ((row >> 1) & 3)) << 3);
        srcA[r] = offA[row] + cs_;
        srcB[r] = offB[row] + cs_;
        dA[r] = row * 32 + (tid & 3) * 8;          // linear dest (ushorts)
        dB[r] = 4096 + dA[r];
    }

    // swizzled read offsets (ushort units)
    int aoff[4], boff[4];
#pragma unroll
    for (int i = 0; i < 4; ++i) {
        int ra = wM * 64 + i * 16 + lr;
        aoff[i] = ra * 32 + ((lg ^ ((ra >> 1) & 3)) << 3);
        int rb = wN * 64 + i * 16 + lr;
        boff[i] = 4096 + rb * 32 + ((lg ^ ((rb >> 1) & 3)) << 3);
    }

    f32x4_t acc[4][4];
#pragma unroll
    for (int i = 0; i < 4; ++i)
#pragma unroll
        for (int j = 0; j < 4; ++j) acc[i][j] = (f32x4_t){0.f, 0.f, 0.f, 0.f};

    for (int t = 0; t < 24; ++t) {
        const int k0 = t * 32;
        {
            float4 f0, f1;
#pragma unroll
            for (int r = 0; r < 2; ++r) {
                f0 = *(const float4*)(z1 + srcA[r] + k0);
                f1 = *(const float4*)(z1 + srcA[r] + k0 + 4);
                *(u16x8_t*)&smem[dA[r]] = cvt8(f0, f1);
            }
#pragma unroll
            for (int r = 0; r < 2; ++r) {
                f0 = *(const float4*)(z2 + srcB[r] + k0);
                f1 = *(const float4*)(z2 + srcB[r] + k0 + 4);
                *(u16x8_t*)&smem[dB[r]] = cvt8(f0, f1);
            }
        }
        __syncthreads();
        {
            bf16x8_t av[4], bv[4];
#pragma unroll
            for (int i = 0; i < 4; ++i) av[i] = *(const bf16x8_t*)&smem[aoff[i]];
#pragma unroll
            for (int j = 0; j < 4; ++j) bv[j] = *(const bf16x8_t*)&smem[boff[j]];
            __builtin_amdgcn_s_setprio(1);
#pragma unroll
            for (int i = 0; i < 4; ++i)
#pragma unroll
                for (int j = 0; j < 4; ++j)
                    acc[i][j] = __builtin_amdgcn_mfma_f32_16x16x32_bf16(
                        av[i], bv[j], acc[i][j], 0, 0, 0);
            __builtin_amdgcn_s_setprio(0);
        }
        __syncthreads();
    }

    // Epilogue: L = acc*inv_tau; exp row/col partial sums; diag.
    const int rowbase = brow * 128 + wM * 64;
    const int colbase = bcol * 128 + wN * 64;
    float colacc[4] = {0.f, 0.f, 0.f, 0.f};
#pragma unroll
    for (int i = 0; i < 4; ++i) {
#pragma unroll
        for (int reg = 0; reg < 4; ++reg) {
            int row = rowbase + i * 16 + lg * 4 + reg;
            bool rv = row < M;
            float rp = 0.f;
#pragma unroll
            for (int j = 0; j < 4; ++j) {
                int col = colbase + j * 16 + lr;
                float L = acc[i][j][reg] * inv_tau;
                float e = (rv && (col < M)) ? __expf(L) : 0.f;
                rp += e;
                colacc[j] += e;
                if (rv && row == col) dg[batch * M + row] = L;
            }
#pragma unroll
            for (int s = 1; s < 16; s <<= 1) rp += __shfl_xor(rp, s);
            if (lr == 0 && rv) atomicAdd(&rs[batch * M + row], rp);
        }
    }
#pragma unroll
    for (int j = 0; j < 4; ++j) {
        float cv = colacc[j];
        cv += __shfl_xor(cv, 16);
        cv += __shfl_xor(cv, 32);
        int col = colbase + j * 16 + lr;
        if (lg == 0 && col < M) atomicAdd(&cs[batch * M + col], cv);
    }
}

// parallel finalize; out[0] pre-zeroed, one atomicAdd per block.
__global__ __launch_bounds__(256) void finalize_kernel(
    const float* __restrict__ ws, float* __restrict__ out) {
    const float* rs_ov = ws;
    const float* cs_ov = ws + 18432;
    const float* dg_ov = ws + 36864;
    const float* rs_t  = ws + 55296;
    const float* cs_t  = ws + 92160;
    const float* dg_t  = ws + 129024;
    const int g0 = blockIdx.x * blockDim.x + threadIdx.x;
    const int gs = gridDim.x * blockDim.x;
    float s_ov = 0.f, s_t = 0.f;
    for (int i = g0; i < 18432; i += gs)
        s_ov += logf(rs_ov[i]) + logf(cs_ov[i]) - 2.f * dg_ov[i];
    for (int i = g0; i < 36864; i += gs)
        s_t += logf(rs_t[i]) + logf(cs_t[i]) - 2.f * dg_t[i];
    float c = 0.5f * s_ov / 18432.f + 0.05f * s_t / 36864.f;
#pragma unroll
    for (int s = 1; s < 64; s <<= 1) c += __shfl_xor(c, s);
    __shared__ float red[4];
    int wv = threadIdx.x >> 6;
    if ((threadIdx.x & 63) == 0) red[wv] = c;
    __syncthreads();
    if (threadIdx.x == 0)
        atomicAdd(out, red[0] + red[1] + red[2] + red[3]);
}

extern "C" void kernel_launch(void* const* d_in, const int* in_sizes, int n_in,
                              void* d_out, int out_size, void* d_ws, size_t ws_size,
                              hipStream_t stream) {
    const float* z1 = (const float*)d_in[0];
    const float* z2 = (const float*)d_in[1];
    float* out = (float*)d_out;
    float* ws  = (float*)d_ws;

    const size_t ACC_B = 165888 * sizeof(float);
    hipMemsetAsync(d_ws, 0, ACC_B, stream);
    hipMemsetAsync(d_out, 0, sizeof(float), stream);

    gemm128_lse_all<<<4192, 256, 0, stream>>>(z1, z2, ws);
    finalize_kernel<<<16, 256, 0, stream>>>(ws, out);
}

// Round 16
// 187.142 us; speedup vs baseline: 7.0658x; 7.0658x over previous
//
#include <hip/hip_runtime.h>
#include <hip/hip_bf16.h>

typedef __attribute__((ext_vector_type(8))) short bf16x8_t;
typedef __attribute__((ext_vector_type(4))) float f32x4_t;
typedef __attribute__((ext_vector_type(8))) unsigned short u16x8_t;

__device__ inline unsigned short bfr(float f) {
    __hip_bfloat16 h = __float2bfloat16(f);   // RNE
    return *reinterpret_cast<unsigned short*>(&h);
}

__device__ inline u16x8_t cvt8(float4 x, float4 y) {
    u16x8_t v;
    v[0] = bfr(x.x); v[1] = bfr(x.y); v[2] = bfr(x.z); v[3] = bfr(x.w);
    v[4] = bfr(y.x); v[5] = bfr(y.y); v[6] = bfr(y.z); v[7] = bfr(y.w);
    return v;
}

// ---- merged 128x128-tile GEMM+LSE, fused f32->bf16 staging ----------------
// R16 = R13 restored verbatim (session best, 191 us). R14 (256^2/16-wave,
// 204 us), R15 ((256,6) -> 40-VGPR acc spill, 1322 us) both regressed.
// blocks (XCD-swizzled): lb 0..2591 overlap (8 batches x 18x18, supertiled
// 3 sc-groups x (18 brow x 6 bcol) => B-panels L2-resident per sc-group),
// lb 2592..4191 tile (64 batches x 5x5, rows>=576 duplicated & masked).
// Per K64-step: load f32 (A half then B half), cvt->bf16, ds_write 32KB
// single buffer, sync, 16 ds_read_b128 + 32 MFMA, sync. 4 blocks/CU give
// the inter-block latency cover (m114 implicit overlap).
// Swizzle (verified 0-conflict): 16B-chunk phys = logical ^ (row&7) on
// global source + ds_read; LDS layout linear.
// ws float layout:
// [0) rs_ov 18432 | [18432) cs_ov 18432 | [36864) dg_ov 18432
// [55296) rs_t 36864 | [92160) cs_t 36864 | [129024) dg_t 36864 -> 165888
__global__ __launch_bounds__(256, 4) void gemm128_lse_all(
    const float* __restrict__ z1, const float* __restrict__ z2,
    float* __restrict__ ws) {
    const int tid  = threadIdx.x;
    const int lane = tid & 63;
    const int w    = tid >> 6;        // 0..3
    const int wM   = w >> 1;          // 0..1 (rows: wM*64)
    const int wN   = w & 1;           // 0..1 (cols: wN*64)
    const int lr   = lane & 15;
    const int lg   = lane >> 4;       // 0..3

    // T1: XCD-aware bijective swizzle over 4192 = 8*524 blocks
    const int bid = blockIdx.x;
    const int lb  = (bid & 7) * 524 + (bid >> 3);

    int M, batch, brow, bcol;
    float inv_tau;
    float *rs, *cs, *dg;
    bool ov = (lb < 2592);
    if (ov) {
        M = 2304; inv_tau = 1.0f / 0.07f;
        rs = ws; cs = ws + 18432; dg = ws + 36864;
        batch = lb / 324;
        int rem = lb - batch * 324;
        int sc = rem / 108, r2 = rem - sc * 108;
        brow = r2 / 6;
        bcol = sc * 6 + (r2 - brow * 6);
    } else {
        M = 576; inv_tau = 1.0f / 0.2f;
        rs = ws + 55296; cs = ws + 92160; dg = ws + 129024;
        int tl = lb - 2592;
        batch = tl / 25;
        int rem = tl - batch * 25;
        brow = rem / 5;
        bcol = rem - brow * 5;
    }

    __shared__ unsigned short smem[16384];   // A[128][64] + B[128][64], 32 KiB
    __shared__ int offA[128], offB[128];

    if (tid < 128) {
        int r = brow * 128 + tid;
        int off;
        if (ov) {
            int b = r / 288, rm = r % 288, h = rm / 12, j = rm % 12;
            off = ((b * 8 + batch) * 576 + h * 24 + 12 + j) * 768;
        } else {
            off = ((r < M) ? (batch * 576 + r) : (batch * 576)) * 768;
        }
        offA[tid] = off;
    } else {
        int c = bcol * 128 + (tid - 128);
        int off;
        if (ov) {
            int b = c / 288, rm = c % 288, h = rm / 12, j = rm % 12;
            off = ((b * 8 + ((batch + 1) & 7)) * 576 + h * 24 + j) * 768;
        } else {
            off = ((c < M) ? (batch * 576 + c) : (batch * 576)) * 768;
        }
        offB[tid - 128] = off;
    }
    __syncthreads();

    // staging: thread covers rows w*32+ra*8+(lane>>3), logical 16B-chunk
    // (lane&7)^(row&7); in f32 a chunk = 8 floats = 2 float4 loads.
    const int lrow8 = lane >> 3;
    const int cswz  = (((lane & 7) ^ lrow8) << 3);   // element offset in row
    int sA[4], sB[4], dA[4], dB[4];
#pragma unroll
    for (int ra = 0; ra < 4; ++ra) {
        sA[ra] = offA[w * 32 + ra * 8 + lrow8] + cswz;
        sB[ra] = offB[w * 32 + ra * 8 + lrow8] + cswz;
        dA[ra] = (w * 32 + ra * 8) * 64 + lane * 8;          // linear dest
        dB[ra] = 8192 + (w * 32 + ra * 8) * 64 + lane * 8;
    }

    // swizzled read offsets: K-half h, logical chunk h*4+lg, phys ^= row&7.
    int aoff[2][4], boff[2][4];
#pragma unroll
    for (int h = 0; h < 2; ++h) {
#pragma unroll
        for (int i = 0; i < 4; ++i) {
            int ra = wM * 64 + i * 16 + lr;
            aoff[h][i] = ra * 64 + (((h * 4 + lg) ^ (ra & 7)) << 3);
            int rb = wN * 64 + i * 16 + lr;
            boff[h][i] = 8192 + rb * 64 + (((h * 4 + lg) ^ (rb & 7)) << 3);
        }
    }

    f32x4_t acc[4][4];
#pragma unroll
    for (int i = 0; i < 4; ++i)
#pragma unroll
        for (int j = 0; j < 4; ++j) acc[i][j] = (f32x4_t){0.f, 0.f, 0.f, 0.f};

    for (int t = 0; t < 12; ++t) {
        const int k0 = t * 64;
        {
            float4 fa[8];
#pragma unroll
            for (int ra = 0; ra < 4; ++ra) {
                fa[2 * ra]     = *(const float4*)(z1 + sA[ra] + k0);
                fa[2 * ra + 1] = *(const float4*)(z1 + sA[ra] + k0 + 4);
            }
#pragma unroll
            for (int ra = 0; ra < 4; ++ra)
                *(u16x8_t*)&smem[dA[ra]] = cvt8(fa[2 * ra], fa[2 * ra + 1]);
        }
        {
            float4 fb[8];
#pragma unroll
            for (int ra = 0; ra < 4; ++ra) {
                fb[2 * ra]     = *(const float4*)(z2 + sB[ra] + k0);
                fb[2 * ra + 1] = *(const float4*)(z2 + sB[ra] + k0 + 4);
            }
#pragma unroll
            for (int ra = 0; ra < 4; ++ra)
                *(u16x8_t*)&smem[dB[ra]] = cvt8(fb[2 * ra], fb[2 * ra + 1]);
        }
        __syncthreads();
#pragma unroll
        for (int h = 0; h < 2; ++h) {
            bf16x8_t av[4], bv[4];
#pragma unroll
            for (int i = 0; i < 4; ++i) av[i] = *(const bf16x8_t*)&smem[aoff[h][i]];
#pragma unroll
            for (int j = 0; j < 4; ++j) bv[j] = *(const bf16x8_t*)&smem[boff[h][j]];
            __builtin_amdgcn_s_setprio(1);
#pragma unroll
            for (int i = 0; i < 4; ++i)
#pragma unroll
                for (int j = 0; j < 4; ++j)
                    acc[i][j] = __builtin_amdgcn_mfma_f32_16x16x32_bf16(
                        av[i], bv[j], acc[i][j], 0, 0, 0);
            __builtin_amdgcn_s_setprio(0);
        }
        __syncthreads();
    }

    // Epilogue: L = acc*inv_tau; exp row/col partial sums; diag.
    const int rowbase = brow * 128 + wM * 64;
    const int colbase = bcol * 128 + wN * 64;
    float colacc[4] = {0.f, 0.f, 0.f, 0.f};
#pragma unroll
    for (int i = 0; i < 4; ++i) {
#pragma unroll
        for (int reg = 0; reg < 4; ++reg) {
            int row = rowbase + i * 16 + lg * 4 + reg;
            bool rv = row < M;
            float rp = 0.f;
#pragma unroll
            for (int j = 0; j < 4; ++j) {
                int col = colbase + j * 16 + lr;
                float L = acc[i][j][reg] * inv_tau;
                float e = (rv && (col < M)) ? __expf(L) : 0.f;
                rp += e;
                colacc[j] += e;
                if (rv && row == col) dg[batch * M + row] = L;
            }
#pragma unroll
            for (int s = 1; s < 16; s <<= 1) rp += __shfl_xor(rp, s);
            if (lr == 0 && rv) atomicAdd(&rs[batch * M + row], rp);
        }
    }
#pragma unroll
    for (int j = 0; j < 4; ++j) {
        float cv = colacc[j];
        cv += __shfl_xor(cv, 16);
        cv += __shfl_xor(cv, 32);
        int col = colbase + j * 16 + lr;
        if (lg == 0 && col < M) atomicAdd(&cs[batch * M + col], cv);
    }
}

// parallel finalize; out[0] pre-zeroed, one atomicAdd per block.
__global__ __launch_bounds__(256) void finalize_kernel(
    const float* __restrict__ ws, float* __restrict__ out) {
    const float* rs_ov = ws;
    const float* cs_ov = ws + 18432;
    const float* dg_ov = ws + 36864;
    const float* rs_t  = ws + 55296;
    const float* cs_t  = ws + 92160;
    const float* dg_t  = ws + 129024;
    const int g0 = blockIdx.x * blockDim.x + threadIdx.x;
    const int gs = gridDim.x * blockDim.x;
    float s_ov = 0.f, s_t = 0.f;
    for (int i = g0; i < 18432; i += gs)
        s_ov += logf(rs_ov[i]) + logf(cs_ov[i]) - 2.f * dg_ov[i];
    for (int i = g0; i < 36864; i += gs)
        s_t += logf(rs_t[i]) + logf(cs_t[i]) - 2.f * dg_t[i];
    float c = 0.5f * s_ov / 18432.f + 0.05f * s_t / 36864.f;
#pragma unroll
    for (int s = 1; s < 64; s <<= 1) c += __shfl_xor(c, s);
    __shared__ float red[4];
    int wv = threadIdx.x >> 6;
    if ((threadIdx.x & 63) == 0) red[wv] = c;
    __syncthreads();
    if (threadIdx.x == 0)
        atomicAdd(out, red[0] + red[1] + red[2] + red[3]);
}

extern "C" void kernel_launch(void* const* d_in, const int* in_sizes, int n_in,
                              void* d_out, int out_size, void* d_ws, size_t ws_size,
                              hipStream_t stream) {
    const float* z1 = (const float*)d_in[0];
    const float* z2 = (const float*)d_in[1];
    float* out = (float*)d_out;
    float* ws  = (float*)d_ws;

    const size_t ACC_B = 165888 * sizeof(float);
    hipMemsetAsync(d_ws, 0, ACC_B, stream);
    hipMemsetAsync(d_out, 0, sizeof(float), stream);

    gemm128_lse_all<<<4192, 256, 0, stream>>>(z1, z2, ws);
    finalize_kernel<<<16, 256, 0, stream>>>(ws, out);
}